// Round 8
// baseline (616.977 us; speedup 1.0000x reference)
//
#include <hip/hip_runtime.h>

#define N_NODES 100000
#define N_EDGES 1000000
#define CAP     40              // max degree slack: P(Poisson(10) >= 40) ~ 5e-13/node
#define NTILES  (N_NODES / 16)  // 6250 gather/GEMM tiles

typedef __attribute__((ext_vector_type(4))) float float4_t;
typedef __attribute__((ext_vector_type(2))) _Float16 half2v;
typedef __attribute__((ext_vector_type(4))) _Float16 half4v;
typedef __attribute__((ext_vector_type(8))) _Float16 half8v;
typedef unsigned long long ull;

// f32 -> f16 RTNE (values are exp() outputs: positive, normal range)
__device__ __forceinline__ unsigned short f_to_h(float f) {
    union { float f; unsigned int i; } c; c.f = f;
    unsigned int i = c.i;
    unsigned int e = ((i >> 23) & 0xffu) - 112u;       // rebase bias 127 -> 15
    unsigned int m = i & 0x7fffffu;
    unsigned int r = (e << 10) | (m >> 13);
    r += (m >> 12) & 1u;                               // round
    return (unsigned short)r;
}
__device__ __forceinline__ float h_to_f(unsigned short h) {
    union { unsigned int i; float f; } c;
    c.i = (((unsigned int)(h & 0x7fffu)) << 13) + 0x38000000u;
    return c.f;
}
__device__ __forceinline__ unsigned int packh2(float x, float y) {
    half2v h; h.x = (_Float16)x; h.y = (_Float16)y;
    return __builtin_bit_cast(unsigned int, h);
}
__device__ __forceinline__ int clampi(int x) {
    return x < 0 ? 0 : (x >= N_NODES ? N_NODES - 1 : x);
}

// Device-scope grid barrier (single-use counter, zeroed pre-launch).
// Residency of all blocks is guaranteed by occupancy-clamped grid size.
__device__ __forceinline__ void grid_barrier(int* cnt, int nblocks) {
    __syncthreads();
    if (threadIdx.x == 0) {
        __threadfence();                               // agent-scope release
        __hip_atomic_fetch_add(cnt, 1, __ATOMIC_ACQ_REL, __HIP_MEMORY_SCOPE_AGENT);
        while (__hip_atomic_load(cnt, __ATOMIC_ACQUIRE, __HIP_MEMORY_SCOPE_AGENT) < nblocks)
            __builtin_amdgcn_s_sleep(2);
    }
    __syncthreads();
}

// ============ single persistent kernel: all phases, zero launch gaps ========
__global__ __launch_bounds__(256, 8)
void k_mega(const int* __restrict__ tri, const float* __restrict__ ent,
            const float* __restrict__ attf, const float* __restrict__ valf,
            const float* __restrict__ aw, const float* __restrict__ abp,
            const float* __restrict__ W,
            int* __restrict__ ctrl,            // [0]=bar1 [1]=bar2 [2]=tile ctr
            int* __restrict__ cursor, float* __restrict__ s_ent, float* __restrict__ s_att,
            unsigned short* __restrict__ attb, unsigned short* __restrict__ valb,
            unsigned short* __restrict__ Wt, ull* __restrict__ edges,
            float* __restrict__ out) {
    int tid = threadIdx.x;
    int gtid = (int)blockIdx.x * 256 + tid;
    int gsz = (int)gridDim.x * 256;
    int l32 = tid & 31;

    // ---------- Phase 1: cursor zero + Wt prep + per-node score dots ----------
    for (int i = gtid; i < N_NODES; i += gsz) cursor[i] = 0;
    for (int i = gtid; i < 192 * 128; i += gsz) {
        int c = i / 192, k = i - c * 192;
        Wt[i] = __builtin_bit_cast(unsigned short, (_Float16)W[k * 128 + c]);
    }
    {
        const float4_t* aw4 = (const float4_t*)aw;
        float4_t we4 = aw4[l32];
        float4_t wa4 = aw4[32 + l32];
        int halfid = ((int)blockIdx.x << 3) + (tid >> 5);
        int nstep = (int)gridDim.x << 3;
        for (int node = halfid; node < N_NODES; node += nstep) {
            float4_t e4 = ((const float4_t*)ent)[(size_t)node * 32 + l32];
            float4_t a4 = ((const float4_t*)attf)[(size_t)node * 32 + l32];
            float se = e4.x * we4.x + e4.y * we4.y + e4.z * we4.z + e4.w * we4.w;
            float sa = a4.x * wa4.x + a4.y * wa4.y + a4.z * wa4.z + a4.w * wa4.w;
#pragma unroll
            for (int off = 16; off >= 1; off >>= 1) {  // stays within 32-lane half
                se += __shfl_xor(se, off, 64);
                sa += __shfl_xor(sa, off, 64);
            }
            if (l32 == 0) { s_ent[node] = se; s_att[node] = sa; }
        }
    }
    grid_barrier(&ctrl[0], (int)gridDim.x);

    // ---------- Phase 2: f16 table conversion CONCURRENT with placement ------
    // Conversion = streaming BW work; placement = atomic-latency work. Mixed in
    // one phase, other waves' conversion traffic hides the atomic round-trips.
    {
        int halfid = ((int)blockIdx.x << 3) + (tid >> 5);
        int nstep = (int)gridDim.x << 3;
        for (int node = halfid; node < N_NODES; node += nstep) {
            float4_t a4 = ((const float4_t*)attf)[(size_t)node * 32 + l32];
            float2 v2 = ((const float2*)valf)[(size_t)node * 32 + l32];
            uint2 pk; pk.x = packh2(a4.x, a4.y); pk.y = packh2(a4.z, a4.w);
            *(uint2*)(attb + (size_t)node * 128 + l32 * 4) = pk;
            ((unsigned int*)valb)[(size_t)node * 32 + l32] = packh2(v2.x, v2.y);
        }
        float ab = abp[0];
        for (int e = gtid; e < N_EDGES; e += gsz) {
            int h = clampi(tri[3 * e]);
            int a = clampi(tri[3 * e + 1]);
            int v = clampi(tri[3 * e + 2]);
            float s = s_ent[h] + s_att[a] + ab;
            s = s > 0.f ? s : 0.2f * s;                // leaky_relu(0.2)
            float sc = __expf(s);
            int slot = atomicAdd(&cursor[h], 1);
            if (slot < CAP) {
                ull pk = (ull)(unsigned)a | ((ull)(unsigned)v << 17) | ((ull)f_to_h(sc) << 34);
                __builtin_nontemporal_store(pk, edges + (size_t)h * CAP + slot);
            }
        }
    }
    grid_barrier(&ctrl[1], (int)gridDim.x);

    // ---------- Phase 3: gather + GEMM, dynamic tile claiming ----------
    __shared__ unsigned short Gl[16][200];
    __shared__ int s_tile;
    int w = tid >> 6, lane = tid & 63;
    int grp = lane >> 4, l = lane & 15;
    const half8v* ap = (const half8v*)attb;
    const half4v* vp = (const half4v*)valb;
    for (;;) {
        __syncthreads();                               // protect Gl reuse
        if (tid == 0) s_tile = atomicAdd(&ctrl[2], 1);
        __syncthreads();
        int tile = s_tile;
        if (tile >= NTILES) break;                     // uniform across block
        int base = tile * 16;
        int node = base + w * 4 + grp;                 // group owns this node
        int src = grp << 4;
        int cnt = cursor[node]; cnt = cnt > CAP ? CAP : cnt;
        size_t beg = (size_t)node * CAP;

        half8v accA = {};
        half4v accV = {};
        float rsum = 0.f;
        int nbat = (cnt + 15) >> 4;
        for (int b = 0; b < nbat; ++b) {
            int idx = b * 16 + l;
            ull edreg = __builtin_nontemporal_load(edges + beg + (idx < cnt ? idx : 0));
            int lim = cnt - b * 16; lim = lim > 16 ? 16 : lim;
#pragma unroll
            for (int c = 0; c < 4; ++c) {
                int j0 = c * 4;
                if (j0 < lim) {                        // per-lane guard: exec-masks
                    bool m1 = j0 + 1 < lim, m2 = j0 + 2 < lim, m3 = j0 + 3 < lim;
                    ull e0 = __shfl(edreg, src | j0, 64);
                    ull e1 = __shfl(edreg, src | (m1 ? j0 + 1 : 0), 64);
                    ull e2 = __shfl(edreg, src | (m2 ? j0 + 2 : 0), 64);
                    ull e3 = __shfl(edreg, src | (m3 ? j0 + 3 : 0), 64);
                    int a0 = (int)(e0 & 0x1FFFFu), v0 = (int)((e0 >> 17) & 0x1FFFFu);
                    int a1 = m1 ? (int)(e1 & 0x1FFFFu) : 0, v1 = m1 ? (int)((e1 >> 17) & 0x1FFFFu) : 0;
                    int a2 = m2 ? (int)(e2 & 0x1FFFFu) : 0, v2 = m2 ? (int)((e2 >> 17) & 0x1FFFFu) : 0;
                    int a3 = m3 ? (int)(e3 & 0x1FFFFu) : 0, v3 = m3 ? (int)((e3 >> 17) & 0x1FFFFu) : 0;
                    _Float16 s0 = __builtin_bit_cast(_Float16, (unsigned short)(e0 >> 34));
                    _Float16 s1 = m1 ? __builtin_bit_cast(_Float16, (unsigned short)(e1 >> 34)) : (_Float16)0.f;
                    _Float16 s2 = m2 ? __builtin_bit_cast(_Float16, (unsigned short)(e2 >> 34)) : (_Float16)0.f;
                    _Float16 s3 = m3 ? __builtin_bit_cast(_Float16, (unsigned short)(e3 >> 34)) : (_Float16)0.f;
                    // 8 row loads issued back-to-back before any use
                    half8v A0 = ap[a0 * 16 + l];
                    half4v V0 = vp[v0 * 16 + l];
                    half8v A1 = ap[a1 * 16 + l];
                    half4v V1 = vp[v1 * 16 + l];
                    half8v A2 = ap[a2 * 16 + l];
                    half4v V2 = vp[v2 * 16 + l];
                    half8v A3 = ap[a3 * 16 + l];
                    half4v V3 = vp[v3 * 16 + l];
                    rsum += (float)s0 + (float)s1 + (float)s2 + (float)s3;
                    accA += A0 * s0; accV += V0 * s0;  // v_pk_fma_f16
                    accA += A1 * s1; accV += V1 * s1;
                    accA += A2 * s2; accV += V2 * s2;
                    accA += A3 * s3; accV += V3 * s3;
                }
            }
        }
        {
            float inv = rsum > 0.f ? 1.f / rsum : 0.f;
            _Float16 ih = (_Float16)inv;
            unsigned short* gp = &Gl[w * 4 + grp][0];
            *(half8v*)(gp + l * 8) = accA * ih;        // cols l*8 .. l*8+7
            *(half4v*)(gp + 128 + l * 4) = accV * ih;  // cols 128+l*4 ..
        }
        __syncthreads();

        // GEMM (f16 MFMA): rows = 16 tile nodes, wave w -> cols w*32..+31.
        int quad = grp, mn = l;
        float4_t acc0 = {0.f, 0.f, 0.f, 0.f}, acc1 = {0.f, 0.f, 0.f, 0.f};
#pragma unroll
        for (int kt = 0; kt < 6; ++kt) {
            half8v afr = *(const half8v*)(&Gl[mn][quad * 8 + kt * 32]);
            half8v b0 = *(const half8v*)(Wt + (size_t)((w * 2 + 0) * 16 + mn) * 192 + quad * 8 + kt * 32);
            half8v b1 = *(const half8v*)(Wt + (size_t)((w * 2 + 1) * 16 + mn) * 192 + quad * 8 + kt * 32);
            acc0 = __builtin_amdgcn_mfma_f32_16x16x32_f16(afr, b0, acc0, 0, 0, 0);
            acc1 = __builtin_amdgcn_mfma_f32_16x16x32_f16(afr, b1, acc1, 0, 0, 0);
        }
#pragma unroll
        for (int cti = 0; cti < 2; ++cti) {
            float4_t acc = cti ? acc1 : acc0;
            int col = (w * 2 + cti) * 16 + mn;
#pragma unroll
            for (int r = 0; r < 4; ++r) {
                int nd = base + quad * 4 + r;
                float x = acc[r] + __builtin_nontemporal_load(ent + (size_t)nd * 128 + col);
                __builtin_nontemporal_store(x > 0.f ? x : expm1f(x),
                                            out + (size_t)nd * 128 + col);
            }
        }
    }
}

// ===================== fallback multi-kernel path (r6) ======================
__global__ __launch_bounds__(256)
void k_node_scores(const float* __restrict__ ent, const float* __restrict__ attf,
                   const float* __restrict__ valf, const float* __restrict__ aw,
                   float* __restrict__ s_ent, float* __restrict__ s_att,
                   unsigned short* __restrict__ attb, unsigned short* __restrict__ valb) {
    int node = (int)blockIdx.x * 8 + (int)(threadIdx.x >> 5);
    int l32 = threadIdx.x & 31;
    const float4_t* aw4 = (const float4_t*)aw;
    float4_t we4 = aw4[l32];
    float4_t wa4 = aw4[32 + l32];
    float4_t e4 = ((const float4_t*)ent)[(size_t)node * 32 + l32];
    float4_t a4 = ((const float4_t*)attf)[(size_t)node * 32 + l32];
    float2 v2 = ((const float2*)valf)[(size_t)node * 32 + l32];
    if (attb) {
        uint2 pk; pk.x = packh2(a4.x, a4.y); pk.y = packh2(a4.z, a4.w);
        *(uint2*)(attb + (size_t)node * 128 + l32 * 4) = pk;
        ((unsigned int*)valb)[(size_t)node * 32 + l32] = packh2(v2.x, v2.y);
    }
    float se = e4.x * we4.x + e4.y * we4.y + e4.z * we4.z + e4.w * we4.w;
    float sa = a4.x * wa4.x + a4.y * wa4.y + a4.z * wa4.z + a4.w * wa4.w;
#pragma unroll
    for (int off = 16; off >= 1; off >>= 1) {
        se += __shfl_xor(se, off, 64);
        sa += __shfl_xor(sa, off, 64);
    }
    if (l32 == 0) { s_ent[node] = se; s_att[node] = sa; }
}

__global__ __launch_bounds__(256)
void k_prepW(const float* __restrict__ W, unsigned short* __restrict__ Wt) {
    int i = (int)(blockIdx.x * blockDim.x + threadIdx.x);
    if (i >= 192 * 128) return;
    int c = i / 192, k = i - c * 192;
    Wt[i] = __builtin_bit_cast(unsigned short, (_Float16)W[k * 128 + c]);
}

__global__ __launch_bounds__(256)
void k_place(const int* __restrict__ tri, const float* __restrict__ s_ent,
             const float* __restrict__ s_att, const float* __restrict__ abp,
             int* __restrict__ cursor, ull* __restrict__ edges) {
    int e = (int)(blockIdx.x * blockDim.x + threadIdx.x);
    if (e >= N_EDGES) return;
    int h = clampi(tri[3 * e]);
    int a = clampi(tri[3 * e + 1]);
    int v = clampi(tri[3 * e + 2]);
    float s = s_ent[h] + s_att[a] + abp[0];
    s = s > 0.f ? s : 0.2f * s;
    float sc = __expf(s);
    int slot = atomicAdd(&cursor[h], 1);
    if (slot < CAP) {
        ull pk = (ull)(unsigned)a | ((ull)(unsigned)v << 17) | ((ull)f_to_h(sc) << 34);
        __builtin_nontemporal_store(pk, edges + (size_t)h * CAP + slot);
    }
}

__global__ __launch_bounds__(256)
void k_fused_f32(const int* __restrict__ cursor, const ull* __restrict__ edges,
                 const float* __restrict__ attf, const float* __restrict__ valf,
                 const unsigned short* __restrict__ Wt, const float* __restrict__ ent,
                 float* __restrict__ out) {
    __shared__ unsigned short Gl[16][200];
    int w = threadIdx.x >> 6, lane = threadIdx.x & 63;
    int grp = lane >> 4, l = lane & 15;
    int base = (int)blockIdx.x * 16;
    for (int nn = 0; nn < 4; ++nn) {
        int node = base + w * 4 + nn;
        int cnt = cursor[node]; if (cnt > CAP) cnt = CAP;
        size_t beg = (size_t)node * CAP;
        float aa[8] = {0.f, 0.f, 0.f, 0.f, 0.f, 0.f, 0.f, 0.f};
        float av[4] = {0.f, 0.f, 0.f, 0.f};
        float rsum = 0.f;
        for (int j = grp; j < cnt; j += 4) {
            ull ed = edges[beg + j];
            int a = (int)(ed & 0x1FFFFu);
            int v = (int)((ed >> 17) & 0x1FFFFu);
            float sc = h_to_f((unsigned short)(ed >> 34));
            rsum += sc;
            const float4_t* ap = (const float4_t*)(attf + (size_t)a * 128);
            float4_t f0 = ap[l], f1 = ap[16 + l];
            float4_t fv = ((const float4_t*)(valf + (size_t)v * 64))[l];
#pragma unroll
            for (int q = 0; q < 4; ++q) {
                aa[q] += sc * f0[q]; aa[4 + q] += sc * f1[q]; av[q] += sc * fv[q];
            }
        }
#pragma unroll
        for (int q = 0; q < 8; ++q) {
            aa[q] += __shfl_xor(aa[q], 16, 64);
            aa[q] += __shfl_xor(aa[q], 32, 64);
        }
#pragma unroll
        for (int q = 0; q < 4; ++q) {
            av[q] += __shfl_xor(av[q], 16, 64);
            av[q] += __shfl_xor(av[q], 32, 64);
        }
        rsum += __shfl_xor(rsum, 16, 64);
        rsum += __shfl_xor(rsum, 32, 64);
        if (grp == 0) {
            float inv = rsum > 0.f ? 1.f / rsum : 0.f;
            unsigned short* gp = &Gl[w * 4 + nn][0];
            uint2 p0; p0.x = packh2(aa[0] * inv, aa[1] * inv); p0.y = packh2(aa[2] * inv, aa[3] * inv);
            *(uint2*)(gp + l * 4) = p0;
            uint2 p1; p1.x = packh2(aa[4] * inv, aa[5] * inv); p1.y = packh2(aa[6] * inv, aa[7] * inv);
            *(uint2*)(gp + 64 + l * 4) = p1;
            uint2 pv; pv.x = packh2(av[0] * inv, av[1] * inv); pv.y = packh2(av[2] * inv, av[3] * inv);
            *(uint2*)(gp + 128 + l * 4) = pv;
        }
    }
    __syncthreads();
    int quad = grp, mn = l;
    float4_t acc0 = {0.f, 0.f, 0.f, 0.f}, acc1 = {0.f, 0.f, 0.f, 0.f};
#pragma unroll
    for (int kt = 0; kt < 6; ++kt) {
        half8v afr = *(const half8v*)(&Gl[mn][quad * 8 + kt * 32]);
        half8v b0 = *(const half8v*)(Wt + (size_t)((w * 2 + 0) * 16 + mn) * 192 + quad * 8 + kt * 32);
        half8v b1 = *(const half8v*)(Wt + (size_t)((w * 2 + 1) * 16 + mn) * 192 + quad * 8 + kt * 32);
        acc0 = __builtin_amdgcn_mfma_f32_16x16x32_f16(afr, b0, acc0, 0, 0, 0);
        acc1 = __builtin_amdgcn_mfma_f32_16x16x32_f16(afr, b1, acc1, 0, 0, 0);
    }
#pragma unroll
    for (int cti = 0; cti < 2; ++cti) {
        float4_t acc = cti ? acc1 : acc0;
        int col = (w * 2 + cti) * 16 + mn;
#pragma unroll
        for (int r = 0; r < 4; ++r) {
            int node = base + quad * 4 + r;
            float x = acc[r] + ent[(size_t)node * 128 + col];
            out[(size_t)node * 128 + col] = x > 0.f ? x : expm1f(x);
        }
    }
}

extern "C" void kernel_launch(void* const* d_in, const int* in_sizes, int n_in,
                              void* d_out, int out_size, void* d_ws, size_t ws_size,
                              hipStream_t stream) {
    const int*   tri  = (const int*)d_in[0];
    const float* ent  = (const float*)d_in[1];
    const float* attf = (const float*)d_in[2];
    const float* valf = (const float*)d_in[3];
    const float* aw   = (const float*)d_in[4];
    const float* ab   = (const float*)d_in[5];
    const float* W    = (const float*)d_in[6];
    float* out = (float*)d_out;

    char* ws = (char*)d_ws;
    size_t off = 0;
    int*   ctrl   = (int*)(ws + off);   off += 256;    // bar1, bar2, tile ctr (padded)
    int*   cursor = (int*)(ws + off);   off += (size_t)N_NODES * 4;
    float* s_ent  = (float*)(ws + off); off += (size_t)N_NODES * 4;
    float* s_att  = (float*)(ws + off); off += (size_t)N_NODES * 4;
    unsigned short* Wt = (unsigned short*)(ws + off); off += 192 * 128 * 2;
    ull* edges = (ull*)(ws + off);      off += (size_t)N_NODES * CAP * 8;   // 32 MB
    unsigned short* attb = (unsigned short*)(ws + off); off += (size_t)N_NODES * 128 * 2;
    unsigned short* valb = (unsigned short*)(ws + off); off += (size_t)N_NODES * 64 * 2;
    size_t need = off;                                 // ~68.3 MiB (fit proven r3-r6)
    int h16 = ws_size >= need;

    // Occupancy-clamped persistent grid (cached across captures).
    static int s_nb = 0;
    if (s_nb == 0) {
        int occ = 0, ncu = 0, dev = 0;
        if (hipOccupancyMaxActiveBlocksPerMultiprocessor(&occ, k_mega, 256, 0) != hipSuccess || occ <= 0)
            occ = -1;
        (void)hipGetDevice(&dev);
        if (hipDeviceGetAttribute(&ncu, hipDeviceAttributeMultiprocessorCount, dev) != hipSuccess || ncu <= 0)
            ncu = 256;
        s_nb = (occ > 0) ? occ * ncu : -1;
        if (s_nb > 4096) s_nb = 4096;
    }

    if (h16 && s_nb > 0) {
        (void)hipMemsetAsync(ctrl, 0, 12, stream);
        k_mega<<<s_nb, 256, 0, stream>>>(tri, ent, attf, valf, aw, ab, W,
                                         ctrl, cursor, s_ent, s_att,
                                         attb, valb, Wt, edges, out);
    } else {
        (void)hipMemsetAsync(cursor, 0, (size_t)N_NODES * 4, stream);
        k_node_scores<<<N_NODES / 8, 256, 0, stream>>>(ent, attf, valf, aw, s_ent, s_att,
                                                       h16 ? attb : (unsigned short*)nullptr,
                                                       h16 ? valb : (unsigned short*)nullptr);
        k_prepW<<<(192 * 128 + 255) / 256, 256, 0, stream>>>(W, Wt);
        k_place<<<(N_EDGES + 255) / 256, 256, 0, stream>>>(tri, s_ent, s_att, ab, cursor, edges);
        k_fused_f32<<<N_NODES / 16, 256, 0, stream>>>(cursor, edges, attf, valf, Wt, ent, out);
    }
}

// Round 9
// 323.264 us; speedup vs baseline: 1.9086x; 1.9086x over previous
//
#include <hip/hip_runtime.h>

#define N_NODES 100000
#define N_EDGES 1000000
#define CAP     40              // max degree slack: P(Poisson(10) >= 40) ~ 5e-13/node
#define NPREP   2048            // k_prep grid (grid-stride; no residency requirement)

typedef __attribute__((ext_vector_type(4))) float float4_t;
typedef __attribute__((ext_vector_type(2))) _Float16 half2v;
typedef __attribute__((ext_vector_type(4))) _Float16 half4v;
typedef __attribute__((ext_vector_type(8))) _Float16 half8v;
typedef unsigned long long ull;

// f32 -> f16 RTNE (values are exp() outputs: positive, normal range)
__device__ __forceinline__ unsigned short f_to_h(float f) {
    union { float f; unsigned int i; } c; c.f = f;
    unsigned int i = c.i;
    unsigned int e = ((i >> 23) & 0xffu) - 112u;       // rebase bias 127 -> 15
    unsigned int m = i & 0x7fffffu;
    unsigned int r = (e << 10) | (m >> 13);
    r += (m >> 12) & 1u;                               // round
    return (unsigned short)r;
}
__device__ __forceinline__ float h_to_f(unsigned short h) {
    union { unsigned int i; float f; } c;
    c.i = (((unsigned int)(h & 0x7fffu)) << 13) + 0x38000000u;
    return c.f;
}
__device__ __forceinline__ unsigned int packh2(float x, float y) {
    half2v h; h.x = (_Float16)x; h.y = (_Float16)y;
    return __builtin_bit_cast(unsigned int, h);
}
__device__ __forceinline__ int clampi(int x) {
    return x < 0 ? 0 : (x >= N_NODES ? N_NODES - 1 : x);
}

// K1 (fused prep, NO barriers): three independent grid-stride work sets in one
// dispatch. Placement stores only (a,v) -> no dependency on scores -> the
// streaming BW work (scores + f16 conversion + Wt) overlaps the atomic drain.
// Even blocks: scores->place; odd blocks: place->scores (concurrent mix).
__global__ __launch_bounds__(256)
void k_prep(const int* __restrict__ tri, const float* __restrict__ ent,
            const float* __restrict__ attf, const float* __restrict__ valf,
            const float* __restrict__ aw, const float* __restrict__ W,
            float* __restrict__ s_ent, float* __restrict__ s_att,
            unsigned short* __restrict__ attb, unsigned short* __restrict__ valb,
            unsigned short* __restrict__ Wt,
            int* __restrict__ cursor, ull* __restrict__ edges) {
    int bid = (int)blockIdx.x, nbk = (int)gridDim.x, tid = threadIdx.x;
    bool even = (bid & 1) == 0;
#pragma unroll
    for (int pass = 0; pass < 2; ++pass) {
        if ((pass == 0) == even) {
            // ---- scores + f16 table conversion (2 nodes/wave, float4 loads) ----
            int l32 = tid & 31;
            const float4_t* aw4 = (const float4_t*)aw;
            float4_t we4 = aw4[l32];
            float4_t wa4 = aw4[32 + l32];
            int halfid = bid * 8 + (tid >> 5);
            int nstep = nbk * 8;
            for (int node = halfid; node < N_NODES; node += nstep) {
                float4_t e4 = ((const float4_t*)ent)[(size_t)node * 32 + l32];
                float4_t a4 = ((const float4_t*)attf)[(size_t)node * 32 + l32];
                float2 v2 = ((const float2*)valf)[(size_t)node * 32 + l32];
                uint2 pk; pk.x = packh2(a4.x, a4.y); pk.y = packh2(a4.z, a4.w);
                *(uint2*)(attb + (size_t)node * 128 + l32 * 4) = pk;
                ((unsigned int*)valb)[(size_t)node * 32 + l32] = packh2(v2.x, v2.y);
                float se = e4.x * we4.x + e4.y * we4.y + e4.z * we4.z + e4.w * we4.w;
                float sa = a4.x * wa4.x + a4.y * wa4.y + a4.z * wa4.z + a4.w * wa4.w;
#pragma unroll
                for (int off = 16; off >= 1; off >>= 1) {   // within 32-lane half
                    se += __shfl_xor(se, off, 64);
                    sa += __shfl_xor(sa, off, 64);
                }
                if (l32 == 0) { s_ent[node] = se; s_att[node] = sa; }
            }
            // ---- Wt transpose (cheap) ----
            for (int i = bid * 256 + tid; i < 192 * 128; i += nbk * 256) {
                int c = i / 192, k = i - c * 192;
                Wt[i] = __builtin_bit_cast(unsigned short, (_Float16)W[k * 128 + c]);
            }
        } else {
            // ---- placement: (a,v) only, 4 edges/thread, 1 atomic each ----
            const int4* t4 = (const int4*)tri;
            for (int t = bid * 256 + tid; t < N_EDGES / 4; t += nbk * 256) {
                int4 w0 = t4[3 * t], w1 = t4[3 * t + 1], w2 = t4[3 * t + 2];
                int hs[4] = {w0.x, w0.w, w1.z, w2.y};
                int as[4] = {w0.y, w1.x, w1.w, w2.z};
                int vs[4] = {w0.z, w1.y, w2.x, w2.w};
#pragma unroll
                for (int i = 0; i < 4; ++i) {
                    int h = clampi(hs[i]), a = clampi(as[i]), v = clampi(vs[i]);
                    int slot = atomicAdd(&cursor[h], 1);
                    if (slot < CAP) {
                        ull pk = (ull)(unsigned)a | ((ull)(unsigned)v << 17);
                        __builtin_nontemporal_store(pk, edges + (size_t)h * CAP + slot);
                    }
                }
            }
        }
    }
}

// K2 (fused gather + GEMM): r6 structure + in-gather score recompute.
// Per edge: sc = exp(lrelu(s_ent[h] + s_att[a] + b)) — s_ent[h] uniform per
// node, s_att L2-resident 400KB (broadcast 4B load), exp is vector-wide VALU.
// 12 loads in flight per 4-edge chunk (4 s_att + 8 rows).
__global__ __launch_bounds__(256)
void k_fused_h(const int* __restrict__ cursor, const ull* __restrict__ edges,
               const float* __restrict__ s_ent, const float* __restrict__ s_att,
               const float* __restrict__ abp,
               const unsigned short* __restrict__ attb, const unsigned short* __restrict__ valb,
               const unsigned short* __restrict__ Wt, const float* __restrict__ ent,
               float* __restrict__ out) {
    __shared__ unsigned short Gl[16][200];
    int w = threadIdx.x >> 6, lane = threadIdx.x & 63;
    int grp = lane >> 4, l = lane & 15;
    int base = (int)blockIdx.x * 16;
    int node = base + w * 4 + grp;                     // group owns this node
    int src = grp << 4;

    int cnt = cursor[node]; cnt = cnt > CAP ? CAP : cnt;
    size_t beg = (size_t)node * CAP;
    const half8v* ap = (const half8v*)attb;
    const half4v* vp = (const half4v*)valb;
    float seh = s_ent[node] + abp[0];

    half8v accA = {};
    half4v accV = {};
    float rsum = 0.f;
    int nbat = (cnt + 15) >> 4;
    for (int b = 0; b < nbat; ++b) {
        int idx = b * 16 + l;
        ull edreg = __builtin_nontemporal_load(edges + beg + (idx < cnt ? idx : 0));
        int lim = cnt - b * 16; lim = lim > 16 ? 16 : lim;
#pragma unroll
        for (int c = 0; c < 4; ++c) {
            int j0 = c * 4;
            if (j0 < lim) {                            // per-lane guard: exec-masks
                bool m1 = j0 + 1 < lim, m2 = j0 + 2 < lim, m3 = j0 + 3 < lim;
                ull e0 = __shfl(edreg, src | j0, 64);
                ull e1 = __shfl(edreg, src | (m1 ? j0 + 1 : 0), 64);
                ull e2 = __shfl(edreg, src | (m2 ? j0 + 2 : 0), 64);
                ull e3 = __shfl(edreg, src | (m3 ? j0 + 3 : 0), 64);
                int a0 = (int)(e0 & 0x1FFFFu), v0 = (int)((e0 >> 17) & 0x1FFFFu);
                int a1 = m1 ? (int)(e1 & 0x1FFFFu) : 0, v1 = m1 ? (int)((e1 >> 17) & 0x1FFFFu) : 0;
                int a2 = m2 ? (int)(e2 & 0x1FFFFu) : 0, v2 = m2 ? (int)((e2 >> 17) & 0x1FFFFu) : 0;
                int a3 = m3 ? (int)(e3 & 0x1FFFFu) : 0, v3 = m3 ? (int)((e3 >> 17) & 0x1FFFFu) : 0;
                // issue all 12 loads before any use
                float t0 = s_att[a0], t1 = s_att[a1], t2 = s_att[a2], t3 = s_att[a3];
                half8v A0 = ap[a0 * 16 + l];
                half4v V0 = vp[v0 * 16 + l];
                half8v A1 = ap[a1 * 16 + l];
                half4v V1 = vp[v1 * 16 + l];
                half8v A2 = ap[a2 * 16 + l];
                half4v V2 = vp[v2 * 16 + l];
                half8v A3 = ap[a3 * 16 + l];
                half4v V3 = vp[v3 * 16 + l];
                float f0 = seh + t0; f0 = f0 > 0.f ? f0 : 0.2f * f0;
                float f1 = seh + t1; f1 = f1 > 0.f ? f1 : 0.2f * f1;
                float f2 = seh + t2; f2 = f2 > 0.f ? f2 : 0.2f * f2;
                float f3 = seh + t3; f3 = f3 > 0.f ? f3 : 0.2f * f3;
                float sc0 = __expf(f0);
                float sc1 = m1 ? __expf(f1) : 0.f;
                float sc2 = m2 ? __expf(f2) : 0.f;
                float sc3 = m3 ? __expf(f3) : 0.f;
                _Float16 s0 = (_Float16)sc0, s1 = (_Float16)sc1;
                _Float16 s2 = (_Float16)sc2, s3 = (_Float16)sc3;
                rsum += (float)s0 + (float)s1 + (float)s2 + (float)s3;
                accA += A0 * s0; accV += V0 * s0;      // v_pk_fma_f16
                accA += A1 * s1; accV += V1 * s1;
                accA += A2 * s2; accV += V2 * s2;
                accA += A3 * s3; accV += V3 * s3;
            }
        }
    }
    // no reduce needed: each lane holds final cols, rsum replicated in-group
    {
        float inv = rsum > 0.f ? 1.f / rsum : 0.f;
        _Float16 ih = (_Float16)inv;
        unsigned short* gp = &Gl[w * 4 + grp][0];
        *(half8v*)(gp + l * 8) = accA * ih;            // cols l*8 .. l*8+7
        *(half4v*)(gp + 128 + l * 4) = accV * ih;      // cols 128+l*4 ..
    }
    __syncthreads();

    // GEMM phase (f16 MFMA): rows = 16 block nodes, wave w -> cols w*32..+31.
    int quad = grp, mn = l;
    float4_t acc0 = {0.f, 0.f, 0.f, 0.f}, acc1 = {0.f, 0.f, 0.f, 0.f};
#pragma unroll
    for (int kt = 0; kt < 6; ++kt) {
        half8v afr = *(const half8v*)(&Gl[mn][quad * 8 + kt * 32]);
        half8v b0 = *(const half8v*)(Wt + (size_t)((w * 2 + 0) * 16 + mn) * 192 + quad * 8 + kt * 32);
        half8v b1 = *(const half8v*)(Wt + (size_t)((w * 2 + 1) * 16 + mn) * 192 + quad * 8 + kt * 32);
        acc0 = __builtin_amdgcn_mfma_f32_16x16x32_f16(afr, b0, acc0, 0, 0, 0);
        acc1 = __builtin_amdgcn_mfma_f32_16x16x32_f16(afr, b1, acc1, 0, 0, 0);
    }
#pragma unroll
    for (int cti = 0; cti < 2; ++cti) {
        float4_t acc = cti ? acc1 : acc0;
        int col = (w * 2 + cti) * 16 + mn;
#pragma unroll
        for (int r = 0; r < 4; ++r) {
            int nd = base + quad * 4 + r;
            float x = acc[r] + __builtin_nontemporal_load(ent + (size_t)nd * 128 + col);
            __builtin_nontemporal_store(x > 0.f ? x : expm1f(x),
                                        out + (size_t)nd * 128 + col);
        }
    }
}

// ===================== fallback multi-kernel path (r6) ======================
__global__ __launch_bounds__(256)
void k_node_scores(const float* __restrict__ ent, const float* __restrict__ attf,
                   const float* __restrict__ valf, const float* __restrict__ aw,
                   float* __restrict__ s_ent, float* __restrict__ s_att) {
    int node = (int)blockIdx.x * 8 + (int)(threadIdx.x >> 5);
    int l32 = threadIdx.x & 31;
    const float4_t* aw4 = (const float4_t*)aw;
    float4_t we4 = aw4[l32];
    float4_t wa4 = aw4[32 + l32];
    float4_t e4 = ((const float4_t*)ent)[(size_t)node * 32 + l32];
    float4_t a4 = ((const float4_t*)attf)[(size_t)node * 32 + l32];
    float se = e4.x * we4.x + e4.y * we4.y + e4.z * we4.z + e4.w * we4.w;
    float sa = a4.x * wa4.x + a4.y * wa4.y + a4.z * wa4.z + a4.w * wa4.w;
#pragma unroll
    for (int off = 16; off >= 1; off >>= 1) {
        se += __shfl_xor(se, off, 64);
        sa += __shfl_xor(sa, off, 64);
    }
    if (l32 == 0) { s_ent[node] = se; s_att[node] = sa; }
}

__global__ __launch_bounds__(256)
void k_prepW(const float* __restrict__ W, unsigned short* __restrict__ Wt) {
    int i = (int)(blockIdx.x * blockDim.x + threadIdx.x);
    if (i >= 192 * 128) return;
    int c = i / 192, k = i - c * 192;
    Wt[i] = __builtin_bit_cast(unsigned short, (_Float16)W[k * 128 + c]);
}

__global__ __launch_bounds__(256)
void k_place_sc(const int* __restrict__ tri, const float* __restrict__ s_ent,
                const float* __restrict__ s_att, const float* __restrict__ abp,
                int* __restrict__ cursor, ull* __restrict__ edges) {
    int e = (int)(blockIdx.x * blockDim.x + threadIdx.x);
    if (e >= N_EDGES) return;
    int h = clampi(tri[3 * e]);
    int a = clampi(tri[3 * e + 1]);
    int v = clampi(tri[3 * e + 2]);
    float s = s_ent[h] + s_att[a] + abp[0];
    s = s > 0.f ? s : 0.2f * s;
    float sc = __expf(s);
    int slot = atomicAdd(&cursor[h], 1);
    if (slot < CAP) {
        ull pk = (ull)(unsigned)a | ((ull)(unsigned)v << 17) | ((ull)f_to_h(sc) << 34);
        __builtin_nontemporal_store(pk, edges + (size_t)h * CAP + slot);
    }
}

__global__ __launch_bounds__(256)
void k_fused_f32(const int* __restrict__ cursor, const ull* __restrict__ edges,
                 const float* __restrict__ attf, const float* __restrict__ valf,
                 const unsigned short* __restrict__ Wt, const float* __restrict__ ent,
                 float* __restrict__ out) {
    __shared__ unsigned short Gl[16][200];
    int w = threadIdx.x >> 6, lane = threadIdx.x & 63;
    int grp = lane >> 4, l = lane & 15;
    int base = (int)blockIdx.x * 16;
    for (int nn = 0; nn < 4; ++nn) {
        int node = base + w * 4 + nn;
        int cnt = cursor[node]; if (cnt > CAP) cnt = CAP;
        size_t beg = (size_t)node * CAP;
        float aa[8] = {0.f, 0.f, 0.f, 0.f, 0.f, 0.f, 0.f, 0.f};
        float av[4] = {0.f, 0.f, 0.f, 0.f};
        float rsum = 0.f;
        for (int j = grp; j < cnt; j += 4) {
            ull ed = edges[beg + j];
            int a = (int)(ed & 0x1FFFFu);
            int v = (int)((ed >> 17) & 0x1FFFFu);
            float sc = h_to_f((unsigned short)(ed >> 34));
            rsum += sc;
            const float4_t* ap = (const float4_t*)(attf + (size_t)a * 128);
            float4_t f0 = ap[l], f1 = ap[16 + l];
            float4_t fv = ((const float4_t*)(valf + (size_t)v * 64))[l];
#pragma unroll
            for (int q = 0; q < 4; ++q) {
                aa[q] += sc * f0[q]; aa[4 + q] += sc * f1[q]; av[q] += sc * fv[q];
            }
        }
#pragma unroll
        for (int q = 0; q < 8; ++q) {
            aa[q] += __shfl_xor(aa[q], 16, 64);
            aa[q] += __shfl_xor(aa[q], 32, 64);
        }
#pragma unroll
        for (int q = 0; q < 4; ++q) {
            av[q] += __shfl_xor(av[q], 16, 64);
            av[q] += __shfl_xor(av[q], 32, 64);
        }
        rsum += __shfl_xor(rsum, 16, 64);
        rsum += __shfl_xor(rsum, 32, 64);
        if (grp == 0) {
            float inv = rsum > 0.f ? 1.f / rsum : 0.f;
            unsigned short* gp = &Gl[w * 4 + nn][0];
            uint2 p0; p0.x = packh2(aa[0] * inv, aa[1] * inv); p0.y = packh2(aa[2] * inv, aa[3] * inv);
            *(uint2*)(gp + l * 4) = p0;
            uint2 p1; p1.x = packh2(aa[4] * inv, aa[5] * inv); p1.y = packh2(aa[6] * inv, aa[7] * inv);
            *(uint2*)(gp + 64 + l * 4) = p1;
            uint2 pv; pv.x = packh2(av[0] * inv, av[1] * inv); pv.y = packh2(av[2] * inv, av[3] * inv);
            *(uint2*)(gp + 128 + l * 4) = pv;
        }
    }
    __syncthreads();
    int quad = grp, mn = l;
    float4_t acc0 = {0.f, 0.f, 0.f, 0.f}, acc1 = {0.f, 0.f, 0.f, 0.f};
#pragma unroll
    for (int kt = 0; kt < 6; ++kt) {
        half8v afr = *(const half8v*)(&Gl[mn][quad * 8 + kt * 32]);
        half8v b0 = *(const half8v*)(Wt + (size_t)((w * 2 + 0) * 16 + mn) * 192 + quad * 8 + kt * 32);
        half8v b1 = *(const half8v*)(Wt + (size_t)((w * 2 + 1) * 16 + mn) * 192 + quad * 8 + kt * 32);
        acc0 = __builtin_amdgcn_mfma_f32_16x16x32_f16(afr, b0, acc0, 0, 0, 0);
        acc1 = __builtin_amdgcn_mfma_f32_16x16x32_f16(afr, b1, acc1, 0, 0, 0);
    }
#pragma unroll
    for (int cti = 0; cti < 2; ++cti) {
        float4_t acc = cti ? acc1 : acc0;
        int col = (w * 2 + cti) * 16 + mn;
#pragma unroll
        for (int r = 0; r < 4; ++r) {
            int node = base + quad * 4 + r;
            float x = acc[r] + ent[(size_t)node * 128 + col];
            out[(size_t)node * 128 + col] = x > 0.f ? x : expm1f(x);
        }
    }
}

extern "C" void kernel_launch(void* const* d_in, const int* in_sizes, int n_in,
                              void* d_out, int out_size, void* d_ws, size_t ws_size,
                              hipStream_t stream) {
    const int*   tri  = (const int*)d_in[0];
    const float* ent  = (const float*)d_in[1];
    const float* attf = (const float*)d_in[2];
    const float* valf = (const float*)d_in[3];
    const float* aw   = (const float*)d_in[4];
    const float* ab   = (const float*)d_in[5];
    const float* W    = (const float*)d_in[6];
    float* out = (float*)d_out;

    char* ws = (char*)d_ws;
    size_t off = 0;
    int*   cursor = (int*)(ws + off);   off += (size_t)N_NODES * 4;
    float* s_ent  = (float*)(ws + off); off += (size_t)N_NODES * 4;
    float* s_att  = (float*)(ws + off); off += (size_t)N_NODES * 4;
    unsigned short* Wt = (unsigned short*)(ws + off); off += 192 * 128 * 2;
    ull* edges = (ull*)(ws + off);      off += (size_t)N_NODES * CAP * 8;   // 32 MB
    unsigned short* attb = (unsigned short*)(ws + off); off += (size_t)N_NODES * 128 * 2;
    unsigned short* valb = (unsigned short*)(ws + off); off += (size_t)N_NODES * 64 * 2;
    size_t need = off;                                 // ~68.3 MiB (fit proven r3-r6)
    int h16 = ws_size >= need;

    (void)hipMemsetAsync(cursor, 0, (size_t)N_NODES * 4, stream);

    if (h16) {
        k_prep<<<NPREP, 256, 0, stream>>>(tri, ent, attf, valf, aw, W,
                                          s_ent, s_att, attb, valb, Wt, cursor, edges);
        k_fused_h<<<N_NODES / 16, 256, 0, stream>>>(cursor, edges, s_ent, s_att, ab,
                                                    attb, valb, Wt, ent, out);
    } else {
        k_node_scores<<<N_NODES / 8, 256, 0, stream>>>(ent, attf, valf, aw, s_ent, s_att);
        k_prepW<<<(192 * 128 + 255) / 256, 256, 0, stream>>>(W, Wt);
        k_place_sc<<<(N_EDGES + 255) / 256, 256, 0, stream>>>(tri, s_ent, s_att, ab, cursor, edges);
        k_fused_f32<<<N_NODES / 16, 256, 0, stream>>>(cursor, edges, attf, valf, Wt, ent, out);
    }
}